// Round 1
// baseline (30560.349 us; speedup 1.0000x reference)
//
#include <hip/hip_runtime.h>
#include <math.h>

#define B_ 128
#define T_ 512
#define I_ 128
#define H_ 1024
#define G4_ 4096
#define KE_ 1152  // I_ + H_

typedef short short8 __attribute__((ext_vector_type(8)));
typedef float f32x4 __attribute__((ext_vector_type(4)));

__device__ __forceinline__ float bf2f(unsigned short u){
  unsigned int x = ((unsigned int)u)<<16; float f; __builtin_memcpy(&f,&x,4); return f;
}
__device__ __forceinline__ unsigned short f2bf(float f){
  unsigned int x; __builtin_memcpy(&x,&f,4);
  x += 0x7fffu + ((x>>16)&1u);
  return (unsigned short)(x>>16);
}
__device__ __forceinline__ float sigm(float x){ return 1.f/(1.f+__expf(-x)); }
__device__ __forceinline__ float tanh_(float x){ return 1.f - 2.f/(1.f+__expf(2.f*x)); }

// ---------------- prepass kernels ----------------

__global__ void k_f32_to_bf16(const float* __restrict__ src, unsigned short* __restrict__ dst, int n){
  int i = blockIdx.x*256 + threadIdx.x;
  if(i < n) dst[i] = f2bf(src[i]);
}

// out[n][k] = k<128 ? Wih[n][k] : Whh[n][k-128]   (bf16, row-major [4096][1152])
__global__ void k_build_wcat(const float* __restrict__ Wih, const float* __restrict__ Whh,
                             unsigned short* __restrict__ out){
  int n = blockIdx.y;
  int k = blockIdx.x*256 + threadIdx.x;
  if(k < KE_){
    float v = (k < I_) ? Wih[n*I_ + k] : Whh[n*H_ + (k - I_)];
    out[n*KE_ + k] = f2bf(v);
  }
}

// Weff[n][k] = dec_Whh[n][k] + sum_j dec_Wih[n][j]*lin_W[j][k]   (bf16 [4096][1024])
__global__ void k_build_weff(const float* __restrict__ Wih, const float* __restrict__ Whh,
                             const float* __restrict__ linW, unsigned short* __restrict__ out){
  int n = blockIdx.y;
  int k = blockIdx.x*256 + threadIdx.x;  // < 1024
  float acc = Whh[n*H_ + k];
  for(int j=0;j<I_;j++) acc += Wih[n*I_ + j] * linW[j*H_ + k];
  out[n*H_ + k] = f2bf(acc);
}

__global__ void k_build_bias(const float* __restrict__ ebih, const float* __restrict__ ebhh,
                             const float* __restrict__ dbih, const float* __restrict__ dbhh,
                             const float* __restrict__ dWih, const float* __restrict__ linb,
                             float* __restrict__ encb, float* __restrict__ decb, float* __restrict__ decbeff){
  int n = blockIdx.x*256 + threadIdx.x;  // < 4096
  encb[n] = ebih[n] + ebhh[n];
  float db = dbih[n] + dbhh[n];
  decb[n] = db;
  float acc = db;
  for(int j=0;j<I_;j++) acc += linb[j]*dWih[n*I_ + j];
  decbeff[n] = acc;
}

__global__ void k_init_state(unsigned short* __restrict__ h0, float* __restrict__ c){
  int i = blockIdx.x*256 + threadIdx.x;  // < 131072
  h0[i] = 0; c[i] = 0.0f;
}

// ---------------- the recurrent step kernel ----------------
// MODE 0 = encoder, MODE 1 = decoder (with folded teacher-forcing).
// 64 blocks x 256 threads (4 waves). Block b owns h-cols [16b,16b+16) and the
// 4 matching 16-col gate strips of g (n = gate*1024 + 16b + ..). Wave w owns
// rows [32w, 32w+32). No LDS, no __syncthreads.
template<int MODE>
__global__ __launch_bounds__(256) void k_step(
    const unsigned short* __restrict__ W,      // [4096][1152]  (enc or dec tf=1)
    const unsigned short* __restrict__ Weff,   // [4096][1024]  (dec tf=0)
    const unsigned short* __restrict__ xbf,    // [B][T][I] bf16
    const unsigned short* __restrict__ hread,  // [B][H] bf16
    unsigned short* __restrict__ hwrite,       // [B][H] bf16
    float* __restrict__ cbuf,                  // [B][H] f32
    const float* __restrict__ bias_enc,        // [4096]
    const float* __restrict__ bias_tf1,        // [4096]
    const float* __restrict__ bias_tf0,        // [4096]
    const int* __restrict__ lengths,           // [B]
    const int* __restrict__ tfmask,            // [T]
    const unsigned short* __restrict__ linwbf, // [128][1024] bf16 (lin_W)
    const float* __restrict__ linb,            // [128]
    float* __restrict__ dout,                  // full d_out base (f32)
    int t)
{
  const int b   = blockIdx.x;      // 0..63
  const int tid = threadIdx.x;
  const int w   = tid >> 6;        // wave 0..3
  const int l   = tid & 63;
  const int lr  = l & 15;          // row/col-within-16
  const int lq  = l >> 4;          // quad 0..3
  const int hc0 = b * 16;

  // ---- select weights / K / x / bias ----
  const unsigned short* Wp; int K; const float* bias; int use_x; int xt;
  if constexpr (MODE == 0){
    Wp = W; K = KE_; bias = bias_enc; use_x = 1; xt = t;
  } else {
    int tf = (t == 0) ? 1 : tfmask[t-1];
    if(tf){ Wp = W;    K = KE_; bias = bias_tf1; use_x = 1; xt = (t==0) ? (T_-1) : (t-1); }
    else  { Wp = Weff; K = H_;  bias = bias_tf0; use_x = 0; xt = 0; }
  }

  // ---- main GEMM: g[128 x 64strips] = [x|h] @ Wp^T ----
  f32x4 acc[2][4];
  #pragma unroll
  for(int rt=0;rt<2;rt++)
    #pragma unroll
    for(int g=0;g<4;g++)
      acc[rt][g] = (f32x4){0.f,0.f,0.f,0.f};

  // B-frag row base: gate g, col n = g*1024 + hc0 + lr ; elem addr n*K + kb + lq*8
  long wrow[4];
  #pragma unroll
  for(int g=0;g<4;g++) wrow[g] = (long)(g*H_ + hc0 + lr)*K + lq*8;

  const int am0 = w*32 + lr;       // A rows for rowtile 0/1
  const int am1 = w*32 + 16 + lr;

  const int nk = K >> 5;
  for(int ks=0; ks<nk; ++ks){
    const int kb = ks*32;
    short8 bfrag[4];
    #pragma unroll
    for(int g=0;g<4;g++)
      bfrag[g] = *(const short8*)(Wp + wrow[g] + kb);

    short8 afrag[2];
    if(use_x && kb < I_){
      afrag[0] = *(const short8*)(xbf + (long)am0*(T_*I_) + (long)xt*I_ + kb + lq*8);
      afrag[1] = *(const short8*)(xbf + (long)am1*(T_*I_) + (long)xt*I_ + kb + lq*8);
    } else {
      const int hk = use_x ? (kb - I_) : kb;
      afrag[0] = *(const short8*)(hread + am0*H_ + hk + lq*8);
      afrag[1] = *(const short8*)(hread + am1*H_ + hk + lq*8);
    }
    #pragma unroll
    for(int g=0;g<4;g++){
      acc[0][g] = __builtin_amdgcn_mfma_f32_16x16x32_bf16(afrag[0], bfrag[g], acc[0][g], 0,0,0);
      acc[1][g] = __builtin_amdgcn_mfma_f32_16x16x32_bf16(afrag[1], bfrag[g], acc[1][g], 0,0,0);
    }
  }

  // ---- epilogue: activations + c/h update ----
  // C-frag: col = lr (rel h-col), row = lq*4 + r (rel within 16-row tile)
  #pragma unroll
  for(int rt=0;rt<2;rt++){
    const int mbase = w*32 + rt*16 + lq*4;
    #pragma unroll
    for(int r=0;r<4;r++){
      const int mm = mbase + r;
      const int hc = hc0 + lr;
      float gi = acc[rt][0][r] + bias[0*H_ + hc];
      float gf = acc[rt][1][r] + bias[1*H_ + hc];
      float gg = acc[rt][2][r] + bias[2*H_ + hc];
      float go = acc[rt][3][r] + bias[3*H_ + hc];
      float i_ = sigm(gi), f_ = sigm(gf), g_ = tanh_(gg), o_ = sigm(go);
      float cp = cbuf[mm*H_ + hc];
      float c2 = f_*cp + i_*g_;
      float h2 = o_ * tanh_(c2);
      if constexpr (MODE == 0){
        const int vm = (t < lengths[mm]) ? 1 : 0;
        float hp = bf2f(hread[mm*H_ + hc]);
        float hn = vm ? h2 : hp;
        float cn = vm ? c2 : cp;
        hwrite[mm*H_ + hc] = f2bf(hn);
        cbuf[mm*H_ + hc]   = cn;
        // encoder_output: d_out region 1
        dout[(long)(B_*T_*I_) + (long)mm*(T_*H_) + (long)t*H_ + hc] = vm ? h2 : 0.f;
      } else {
        hwrite[mm*H_ + hc] = f2bf(h2);
        cbuf[mm*H_ + hc]   = c2;
      }
    }
  }

  // ---- decoder: compute out_{t-1} = h_read @ lin_W^T + lin_b  (wave 0 only) ----
  if constexpr (MODE == 1){
    if(w == 0 && t > 0){
      const int rb = (b >> 3) * 16;   // out row tile
      const int cb = (b & 7) * 16;    // out col tile
      f32x4 aco = (f32x4){0.f,0.f,0.f,0.f};
      for(int ks=0; ks<(H_>>5); ++ks){
        const int kb = ks*32;
        short8 af = *(const short8*)(hread  + (rb+lr)*H_ + kb + lq*8);
        short8 bf = *(const short8*)(linwbf + (cb+lr)*H_ + kb + lq*8);
        aco = __builtin_amdgcn_mfma_f32_16x16x32_bf16(af, bf, aco, 0,0,0);
      }
      #pragma unroll
      for(int r=0;r<4;r++){
        const int mm = rb + lq*4 + r;
        const int cc = cb + lr;
        dout[(long)mm*(T_*I_) + (long)(t-1)*I_ + cc] = aco[r] + linb[cc];
      }
    }
  }
}

// out_511 from the final decoder h
__global__ __launch_bounds__(64) void k_final_out(const unsigned short* __restrict__ hread,
                                                  const unsigned short* __restrict__ linwbf,
                                                  const float* __restrict__ linb,
                                                  float* __restrict__ dout){
  const int b  = blockIdx.x;   // 64
  const int l  = threadIdx.x;
  const int lr = l & 15, lq = l >> 4;
  const int rb = (b >> 3) * 16, cb = (b & 7) * 16;
  f32x4 aco = (f32x4){0.f,0.f,0.f,0.f};
  for(int ks=0; ks<(H_>>5); ++ks){
    const int kb = ks*32;
    short8 af = *(const short8*)(hread  + (rb+lr)*H_ + kb + lq*8);
    short8 bf = *(const short8*)(linwbf + (cb+lr)*H_ + kb + lq*8);
    aco = __builtin_amdgcn_mfma_f32_16x16x32_bf16(af, bf, aco, 0,0,0);
  }
  #pragma unroll
  for(int r=0;r<4;r++){
    const int mm = rb + lq*4 + r;
    const int cc = cb + lr;
    dout[(long)mm*(T_*I_) + (long)(T_-1)*I_ + cc] = aco[r] + linb[cc];
  }
}

// ---------------- host ----------------

extern "C" void kernel_launch(void* const* d_in, const int* in_sizes, int n_in,
                              void* d_out, int out_size, void* d_ws, size_t ws_size,
                              hipStream_t stream) {
  const float* x       = (const float*)d_in[0];
  const float* eWih    = (const float*)d_in[1];
  const float* eWhh    = (const float*)d_in[2];
  const float* ebih    = (const float*)d_in[3];
  const float* ebhh    = (const float*)d_in[4];
  const float* dWih    = (const float*)d_in[5];
  const float* dWhh    = (const float*)d_in[6];
  const float* dbih    = (const float*)d_in[7];
  const float* dbhh    = (const float*)d_in[8];
  const float* linW    = (const float*)d_in[9];
  const float* linb    = (const float*)d_in[10];
  const int*   lengths = (const int*)d_in[11];
  const int*   tfmask  = (const int*)d_in[12];
  float* dout = (float*)d_out;

  char* ws = (char*)d_ws;
  size_t off = 0;
  auto alloc = [&](size_t bytes)->char*{ char* p = ws + off; off = (off + bytes + 255) & ~(size_t)255; return p; };
  unsigned short* xbf   = (unsigned short*)alloc((size_t)B_*T_*I_*2);   // 16 MB
  unsigned short* encW  = (unsigned short*)alloc((size_t)G4_*KE_*2);    // 9.4 MB
  unsigned short* decW  = (unsigned short*)alloc((size_t)G4_*KE_*2);    // 9.4 MB
  unsigned short* weff  = (unsigned short*)alloc((size_t)G4_*H_*2);     // 8.4 MB
  unsigned short* linwb = (unsigned short*)alloc((size_t)I_*H_*2);      // 256 KB
  unsigned short* h0    = (unsigned short*)alloc((size_t)B_*H_*2);
  unsigned short* h1    = (unsigned short*)alloc((size_t)B_*H_*2);
  float*          cbuf  = (float*)alloc((size_t)B_*H_*4);
  float*          encb  = (float*)alloc((size_t)G4_*4);
  float*          decb  = (float*)alloc((size_t)G4_*4);
  float*          decbe = (float*)alloc((size_t)G4_*4);

  // prepass
  k_f32_to_bf16<<<dim3((B_*T_*I_+255)/256), dim3(256), 0, stream>>>(x, xbf, B_*T_*I_);
  k_f32_to_bf16<<<dim3((I_*H_+255)/256),   dim3(256), 0, stream>>>(linW, linwb, I_*H_);
  k_build_wcat<<<dim3(5, G4_), dim3(256), 0, stream>>>(eWih, eWhh, encW);
  k_build_wcat<<<dim3(5, G4_), dim3(256), 0, stream>>>(dWih, dWhh, decW);
  k_build_weff<<<dim3(4, G4_), dim3(256), 0, stream>>>(dWih, dWhh, linW, weff);
  k_build_bias<<<dim3(16), dim3(256), 0, stream>>>(ebih, ebhh, dbih, dbhh, dWih, linb, encb, decb, decbe);
  k_init_state<<<dim3((B_*H_+255)/256), dim3(256), 0, stream>>>(h0, cbuf);

  // encoder: 512 sequential steps
  for(int t=0; t<T_; ++t){
    unsigned short* hr = (t & 1) ? h1 : h0;
    unsigned short* hw = (t & 1) ? h0 : h1;
    k_step<0><<<dim3(64), dim3(256), 0, stream>>>(encW, nullptr, xbf, hr, hw, cbuf,
        encb, nullptr, nullptr, lengths, nullptr, nullptr, nullptr, dout, t);
  }
  // decoder: 512 sequential steps (h state continues in h0 after encoder)
  for(int t=0; t<T_; ++t){
    unsigned short* hr = (t & 1) ? h1 : h0;
    unsigned short* hw = (t & 1) ? h0 : h1;
    k_step<1><<<dim3(64), dim3(256), 0, stream>>>(decW, weff, xbf, hr, hw, cbuf,
        nullptr, decb, decbe, nullptr, tfmask, linwb, linb, dout, t);
  }
  // final projection out_{T-1} from final h (in h0 after 512 steps)
  k_final_out<<<dim3(64), dim3(64), 0, stream>>>(h0, linwb, linb, dout);
}